// Round 1
// baseline (322.906 us; speedup 1.0000x reference)
//
#include <hip/hip_runtime.h>
#include <hip/hip_bf16.h>
#include <math.h>

typedef short bf16x8 __attribute__((ext_vector_type(8)));
typedef float f32x4 __attribute__((ext_vector_type(4)));

#define LROW 72  // padded LDS row (bf16 elems): 144B stride -> 2-way bank alias (free)

__device__ __forceinline__ unsigned short f2bf(float f) {
  union { float f; unsigned int u; } v; v.f = f;
  unsigned int u = v.u;
  unsigned int r = (u + 0x7fffu + ((u >> 16) & 1u)) >> 16;
  return (unsigned short)r;
}

// fp32 -> bf16, 4 elems/thread
__global__ __launch_bounds__(256) void cvt_bf16_kernel(const float* __restrict__ src,
                                                       unsigned short* __restrict__ dst, int n4) {
  int i = blockIdx.x * 256 + threadIdx.x;
  if (i < n4) {
    float4 v = ((const float4*)src)[i];
    ushort4 o;
    o.x = f2bf(v.x); o.y = f2bf(v.y); o.z = f2bf(v.z); o.w = f2bf(v.w);
    ((ushort4*)dst)[i] = o;
  }
}

// C[M][N] = A[M][K] x B[N][K]^T ; A,B bf16 row-major, C fp32. 64x64 tile, 4 waves.
__global__ __launch_bounds__(256) void gemm_bt_kernel(const unsigned short* __restrict__ A,
                                                      const unsigned short* __restrict__ B,
                                                      float* __restrict__ C, int M, int N, int K) {
  __shared__ unsigned short As[64 * LROW];
  __shared__ unsigned short Bs[64 * LROW];
  int tid = threadIdx.x;
  int wave = tid >> 6, lane = tid & 63, l15 = lane & 15, quad = lane >> 4;
  int n0 = blockIdx.x * 64, m0 = blockIdx.y * 64;
  f32x4 acc[4];
#pragma unroll
  for (int i = 0; i < 4; i++) acc[i] = (f32x4){0.f, 0.f, 0.f, 0.f};
  for (int k0 = 0; k0 < K; k0 += 64) {
    __syncthreads();
#pragma unroll
    for (int c0 = 0; c0 < 512; c0 += 256) {
      int c = c0 + tid;
      int row = c >> 3, col8 = (c & 7) * 8;
      *(float4*)(As + row * LROW + col8) =
          *(const float4*)(A + (size_t)(m0 + row) * K + k0 + col8);
      *(float4*)(Bs + row * LROW + col8) =
          *(const float4*)(B + (size_t)(n0 + row) * K + k0 + col8);
    }
    __syncthreads();
#pragma unroll
    for (int kk = 0; kk < 64; kk += 32) {
      bf16x8 af = *(const bf16x8*)(As + (wave * 16 + l15) * LROW + kk + quad * 8);
#pragma unroll
      for (int nt = 0; nt < 4; nt++) {
        bf16x8 bfr = *(const bf16x8*)(Bs + (nt * 16 + l15) * LROW + kk + quad * 8);
        acc[nt] = __builtin_amdgcn_mfma_f32_16x16x32_bf16(af, bfr, acc[nt], 0, 0, 0);
      }
    }
  }
#pragma unroll
  for (int nt = 0; nt < 4; nt++)
#pragma unroll
    for (int r = 0; r < 4; r++)
      C[(size_t)(m0 + wave * 16 + quad * 4 + r) * N + n0 + nt * 16 + l15] = acc[nt][r];
}

// rope + rms-norm for q,k; gate+ve for v. One block per token, wave per head-slot.
// Q scaled by 1.2*0.125 (softmax scale folded), K by 1.2. V written TRANSPOSED [b][kh][d][s].
__global__ __launch_bounds__(256) void qkv_epilogue_kernel(
    const float* __restrict__ qkv, const float* __restrict__ x, const float* __restrict__ ve,
    const float* __restrict__ cosb, const float* __restrict__ sinb,
    const float* __restrict__ wgate, unsigned short* __restrict__ Q,
    unsigned short* __restrict__ K, unsigned short* __restrict__ Vt) {
  int token = blockIdx.x;
  int b = token >> 11, s = token & 2047;
  int wave = threadIdx.x >> 6, d = threadIdx.x & 63;
  float cv = cosb[s * 32 + (d & 31)];
  float sv = sinb[s * 32 + (d & 31)];
  for (int hs = wave; hs < 24; hs += 4) {
    if (hs < 20) {
      bool isq = hs < 16;
      int ch = isq ? hs * 64 + d : 1024 + (hs - 16) * 64 + d;
      float v0 = qkv[(size_t)token * 1536 + ch];
      float other = __shfl_xor(v0, 32, 64);
      // d<32: x1*cos + x2*sin ; d>=32: -x1*sin + x2*cos
      float roped = (d < 32) ? fmaf(v0, cv, other * sv) : fmaf(v0, cv, -other * sv);
      float ss = roped * roped;
#pragma unroll
      for (int off = 1; off < 64; off <<= 1) ss += __shfl_xor(ss, off, 64);
      float scale = rsqrtf(ss * (1.0f / 64.0f) + 1.1920929e-07f) * (isq ? 0.15f : 1.2f);
      unsigned short o = f2bf(roped * scale);
      if (isq) Q[((size_t)(b * 16 + hs) * 2048 + s) * 64 + d] = o;
      else     K[((size_t)(b * 4 + (hs - 16)) * 2048 + s) * 64 + d] = o;
    } else {
      int kh = hs - 20;
      float vv = qkv[(size_t)token * 1536 + 1280 + kh * 64 + d];
      float dot = 0.f;
#pragma unroll
      for (int j = 0; j < 12; j++) dot += x[(size_t)token * 1024 + j] * wgate[kh * 12 + j];
      float gate = 3.0f / (1.0f + __expf(-dot));
      vv = fmaf(gate, ve[(size_t)token * 256 + kh * 64 + d], vv);
      Vt[((size_t)(b * 4 + kh) * 64 + d) * 2048 + s] = f2bf(vv);
    }
  }
}

// causal flash attention, GQA 4:1. Block = (qtile 64, head, batch); 4 waves x 16 queries.
__global__ __launch_bounds__(256) void flash_kernel(const unsigned short* __restrict__ Q,
                                                    const unsigned short* __restrict__ K,
                                                    const unsigned short* __restrict__ Vt,
                                                    unsigned short* __restrict__ Y) {
  __shared__ unsigned short Ks[64 * LROW];       // [key][dim]
  __shared__ unsigned short Vs[64 * LROW];       // [dim][key]  (from transposed global V)
  __shared__ unsigned short Ps[4 * 16 * LROW];   // per-wave P [q][key]
  int qt = blockIdx.x, h = blockIdx.y, b = blockIdx.z;
  int kh = h >> 2;
  int tid = threadIdx.x, wave = tid >> 6, lane = tid & 63, l15 = lane & 15, quad = lane >> 4;
  int q0 = qt * 64;
  const unsigned short* Qp = Q + (((size_t)(b * 16 + h) * 2048) + q0 + wave * 16 + l15) * 64;
  bf16x8 qf0 = *(const bf16x8*)(Qp + quad * 8);
  bf16x8 qf1 = *(const bf16x8*)(Qp + 32 + quad * 8);
  const unsigned short* Kg = K + (size_t)(b * 4 + kh) * 2048 * 64;
  const unsigned short* Vg = Vt + (size_t)(b * 4 + kh) * 64 * 2048;
  unsigned short* Pw = Ps + wave * 16 * LROW;
  f32x4 acc[4];
#pragma unroll
  for (int i = 0; i < 4; i++) acc[i] = (f32x4){0.f, 0.f, 0.f, 0.f};
  float m_i[4] = {-INFINITY, -INFINITY, -INFINITY, -INFINITY};
  float l_i[4] = {0.f, 0.f, 0.f, 0.f};
  for (int kt = 0; kt <= qt; kt++) {
    int k0 = kt * 64;
    __syncthreads();
#pragma unroll
    for (int c0 = 0; c0 < 512; c0 += 256) {
      int c = c0 + tid;
      int row = c >> 3, col8 = (c & 7) * 8;
      *(float4*)(Ks + row * LROW + col8) =
          *(const float4*)(Kg + (size_t)(k0 + row) * 64 + col8);
      *(float4*)(Vs + row * LROW + col8) =
          *(const float4*)(Vg + (size_t)row * 2048 + k0 + col8);
    }
    __syncthreads();
    f32x4 sv[4];
#pragma unroll
    for (int nt = 0; nt < 4; nt++) sv[nt] = (f32x4){0.f, 0.f, 0.f, 0.f};
#pragma unroll
    for (int nt = 0; nt < 4; nt++) {
      bf16x8 b0 = *(const bf16x8*)(Ks + (nt * 16 + l15) * LROW + quad * 8);
      sv[nt] = __builtin_amdgcn_mfma_f32_16x16x32_bf16(qf0, b0, sv[nt], 0, 0, 0);
      bf16x8 b1 = *(const bf16x8*)(Ks + (nt * 16 + l15) * LROW + 32 + quad * 8);
      sv[nt] = __builtin_amdgcn_mfma_f32_16x16x32_bf16(qf1, b1, sv[nt], 0, 0, 0);
    }
    if (kt == qt) {  // diagonal tile: causal mask
      int qg = q0 + wave * 16 + quad * 4;
#pragma unroll
      for (int nt = 0; nt < 4; nt++) {
        int kg = k0 + nt * 16 + l15;
#pragma unroll
        for (int r = 0; r < 4; r++)
          if (kg > qg + r) sv[nt][r] = -INFINITY;
      }
    }
    float alpha[4];
#pragma unroll
    for (int r = 0; r < 4; r++) {
      float m = fmaxf(fmaxf(sv[0][r], sv[1][r]), fmaxf(sv[2][r], sv[3][r]));
#pragma unroll
      for (int off = 1; off < 16; off <<= 1) m = fmaxf(m, __shfl_xor(m, off, 64));
      float mn = fmaxf(m_i[r], m);
      alpha[r] = __expf(m_i[r] - mn);
      m_i[r] = mn;
    }
#pragma unroll
    for (int r = 0; r < 4; r++) {
      float rs = 0.f;
#pragma unroll
      for (int nt = 0; nt < 4; nt++) {
        float p = __expf(sv[nt][r] - m_i[r]);
        sv[nt][r] = p;
        rs += p;
      }
#pragma unroll
      for (int off = 1; off < 16; off <<= 1) rs += __shfl_xor(rs, off, 64);
      l_i[r] = l_i[r] * alpha[r] + rs;
    }
#pragma unroll
    for (int nt = 0; nt < 4; nt++)
#pragma unroll
      for (int r = 0; r < 4; r++) {
        Pw[(quad * 4 + r) * LROW + nt * 16 + l15] = f2bf(sv[nt][r]);
        acc[nt][r] *= alpha[r];
      }
    // per-wave LDS round-trip (C-layout -> A-layout); same-wave DS ordering, no barrier
#pragma unroll
    for (int step = 0; step < 2; step++) {
      bf16x8 pa = *(const bf16x8*)(Pw + l15 * LROW + step * 32 + quad * 8);
#pragma unroll
      for (int nt = 0; nt < 4; nt++) {
        bf16x8 vb = *(const bf16x8*)(Vs + (nt * 16 + l15) * LROW + step * 32 + quad * 8);
        acc[nt] = __builtin_amdgcn_mfma_f32_16x16x32_bf16(pa, vb, acc[nt], 0, 0, 0);
      }
    }
  }
  unsigned short* Yp = Y + ((size_t)b * 2048 + q0 + wave * 16) * 1024 + h * 64;
#pragma unroll
  for (int r = 0; r < 4; r++) {
    float inv = 1.f / l_i[r];
#pragma unroll
    for (int nt = 0; nt < 4; nt++)
      Yp[(size_t)(quad * 4 + r) * 1024 + nt * 16 + l15] = f2bf(acc[nt][r] * inv);
  }
}

extern "C" void kernel_launch(void* const* d_in, const int* in_sizes, int n_in,
                              void* d_out, int out_size, void* d_ws, size_t ws_size,
                              hipStream_t stream) {
  const float* x     = (const float*)d_in[0];
  const float* ve    = (const float*)d_in[1];
  const float* cosb  = (const float*)d_in[2];
  const float* sinb  = (const float*)d_in[3];
  // d_in[4] attn_mask: causal, hard-coded
  const float* Wq    = (const float*)d_in[5];
  const float* Wk    = (const float*)d_in[6];
  const float* Wv    = (const float*)d_in[7];
  const float* Wproj = (const float*)d_in[8];
  const float* Wgate = (const float*)d_in[9];
  float* out = (float*)d_out;
  char* ws = (char*)d_ws;

  size_t o = 0;
  unsigned short* xb   = (unsigned short*)(ws + o); o += (size_t)4096 * 1024 * 2;   // x bf16
  unsigned short* wqkv = (unsigned short*)(ws + o); o += (size_t)1536 * 1024 * 2;   // [Wq;Wk;Wv] bf16
  unsigned short* wpj  = (unsigned short*)(ws + o); o += (size_t)1024 * 1024 * 2;   // Wproj bf16
  float*          qkvf = (float*)(ws + o);          o += (size_t)4096 * 1536 * 4;   // qkv fp32
  unsigned short* Qb   = (unsigned short*)(ws + o); o += (size_t)2 * 16 * 2048 * 64 * 2;
  unsigned short* Kb   = (unsigned short*)(ws + o); o += (size_t)2 * 4 * 2048 * 64 * 2;
  unsigned short* Vb   = (unsigned short*)(ws + o); o += (size_t)2 * 4 * 2048 * 64 * 2; // transposed
  unsigned short* Yb   = (unsigned short*)(ws + o); o += (size_t)4096 * 1024 * 2;   // attn out bf16

  hipLaunchKernelGGL(cvt_bf16_kernel, dim3(4096), dim3(256), 0, stream, x, xb, 1048576);
  hipLaunchKernelGGL(cvt_bf16_kernel, dim3(1024), dim3(256), 0, stream, Wq, wqkv, 262144);
  hipLaunchKernelGGL(cvt_bf16_kernel, dim3(256),  dim3(256), 0, stream, Wk, wqkv + (size_t)1024 * 1024, 65536);
  hipLaunchKernelGGL(cvt_bf16_kernel, dim3(256),  dim3(256), 0, stream, Wv, wqkv + (size_t)1280 * 1024, 65536);
  hipLaunchKernelGGL(cvt_bf16_kernel, dim3(1024), dim3(256), 0, stream, Wproj, wpj, 262144);

  hipLaunchKernelGGL(gemm_bt_kernel, dim3(24, 64), dim3(256), 0, stream, xb, wqkv, qkvf, 4096, 1536, 1024);
  hipLaunchKernelGGL(qkv_epilogue_kernel, dim3(4096), dim3(256), 0, stream,
                     qkvf, x, ve, cosb, sinb, Wgate, Qb, Kb, Vb);
  hipLaunchKernelGGL(flash_kernel, dim3(32, 16, 2), dim3(256), 0, stream, Qb, Kb, Vb, Yb);
  hipLaunchKernelGGL(gemm_bt_kernel, dim3(16, 64), dim3(256), 0, stream, Yb, wpj, out, 4096, 1024, 1024);
}

// Round 2
// 228.482 us; speedup vs baseline: 1.4133x; 1.4133x over previous
//
#include <hip/hip_runtime.h>
#include <hip/hip_bf16.h>
#include <math.h>

typedef short bf16x8 __attribute__((ext_vector_type(8)));
typedef float f32x4 __attribute__((ext_vector_type(4)));

#define LROW 72  // padded LDS row (bf16 elems): 144B stride -> 2-way bank alias (free)

__device__ __forceinline__ unsigned short f2bf(float f) {
  union { float f; unsigned int u; } v; v.f = f;
  unsigned int u = v.u;
  unsigned int r = (u + 0x7fffu + ((u >> 16) & 1u)) >> 16;
  return (unsigned short)r;
}

// fp32 -> bf16, 4 elems/thread
__global__ __launch_bounds__(256) void cvt_bf16_kernel(const float* __restrict__ src,
                                                       unsigned short* __restrict__ dst, int n4) {
  int i = blockIdx.x * 256 + threadIdx.x;
  if (i < n4) {
    float4 v = ((const float4*)src)[i];
    ushort4 o;
    o.x = f2bf(v.x); o.y = f2bf(v.y); o.z = f2bf(v.z); o.w = f2bf(v.w);
    ((ushort4*)dst)[i] = o;
  }
}

// Wq|Wk|Wv fp32 -> contiguous bf16 [1536][1024]; 1024 fp32 per block
__global__ __launch_bounds__(256) void cvt_w_kernel(const float* __restrict__ Wq,
                                                    const float* __restrict__ Wk,
                                                    const float* __restrict__ Wv,
                                                    unsigned short* __restrict__ dst) {
  int blk = blockIdx.x;
  const float* src;
  size_t off;
  if (blk < 1024)      { src = Wq; off = (size_t)blk * 1024; }
  else if (blk < 1280) { src = Wk; off = (size_t)(blk - 1024) * 1024; }
  else                 { src = Wv; off = (size_t)(blk - 1280) * 1024; }
  int i = threadIdx.x;
  float4 v = ((const float4*)(src + off))[i];
  ushort4 o;
  o.x = f2bf(v.x); o.y = f2bf(v.y); o.z = f2bf(v.z); o.w = f2bf(v.w);
  ((ushort4*)(dst + (size_t)blk * 1024))[i] = o;
}

// C[M][N] = A[M][K] x B[N][K]^T ; A,B bf16 row-major, C fp32. 64x64 tile, 4 waves.
__global__ __launch_bounds__(256) void gemm_bt_kernel(const unsigned short* __restrict__ A,
                                                      const unsigned short* __restrict__ B,
                                                      float* __restrict__ C, int M, int N, int K) {
  __shared__ unsigned short As[64 * LROW];
  __shared__ unsigned short Bs[64 * LROW];
  int tid = threadIdx.x;
  int wave = tid >> 6, lane = tid & 63, l15 = lane & 15, quad = lane >> 4;
  int n0 = blockIdx.x * 64, m0 = blockIdx.y * 64;
  f32x4 acc[4];
#pragma unroll
  for (int i = 0; i < 4; i++) acc[i] = (f32x4){0.f, 0.f, 0.f, 0.f};
  for (int k0 = 0; k0 < K; k0 += 64) {
    __syncthreads();
#pragma unroll
    for (int c0 = 0; c0 < 512; c0 += 256) {
      int c = c0 + tid;
      int row = c >> 3, col8 = (c & 7) * 8;
      *(float4*)(As + row * LROW + col8) =
          *(const float4*)(A + (size_t)(m0 + row) * K + k0 + col8);
      *(float4*)(Bs + row * LROW + col8) =
          *(const float4*)(B + (size_t)(n0 + row) * K + k0 + col8);
    }
    __syncthreads();
#pragma unroll
    for (int kk = 0; kk < 64; kk += 32) {
      bf16x8 af = *(const bf16x8*)(As + (wave * 16 + l15) * LROW + kk + quad * 8);
#pragma unroll
      for (int nt = 0; nt < 4; nt++) {
        bf16x8 bfr = *(const bf16x8*)(Bs + (nt * 16 + l15) * LROW + kk + quad * 8);
        acc[nt] = __builtin_amdgcn_mfma_f32_16x16x32_bf16(af, bfr, acc[nt], 0, 0, 0);
      }
    }
  }
#pragma unroll
  for (int nt = 0; nt < 4; nt++)
#pragma unroll
    for (int r = 0; r < 4; r++)
      C[(size_t)(m0 + wave * 16 + quad * 4 + r) * N + n0 + nt * 16 + l15] = acc[nt][r];
}

// rope + rms-norm for q,k; gate+ve for v. One block per token, wave per head-slot.
// Q scaled by 1.2*0.125*log2(e) (softmax scale + exp2 fold), K by 1.2.
// V written TRANSPOSED [b][kh][d][s].
__global__ __launch_bounds__(256) void qkv_epilogue_kernel(
    const float* __restrict__ qkv, const float* __restrict__ x, const float* __restrict__ ve,
    const float* __restrict__ cosb, const float* __restrict__ sinb,
    const float* __restrict__ wgate, unsigned short* __restrict__ Q,
    unsigned short* __restrict__ K, unsigned short* __restrict__ Vt) {
  int token = blockIdx.x;
  int b = token >> 11, s = token & 2047;
  int wave = threadIdx.x >> 6, d = threadIdx.x & 63;
  float cv = cosb[s * 32 + (d & 31)];
  float sv = sinb[s * 32 + (d & 31)];
  for (int hs = wave; hs < 24; hs += 4) {
    if (hs < 20) {
      bool isq = hs < 16;
      int ch = isq ? hs * 64 + d : 1024 + (hs - 16) * 64 + d;
      float v0 = qkv[(size_t)token * 1536 + ch];
      float other = __shfl_xor(v0, 32, 64);
      float roped = (d < 32) ? fmaf(v0, cv, other * sv) : fmaf(v0, cv, -other * sv);
      float ss = roped * roped;
#pragma unroll
      for (int off = 1; off < 64; off <<= 1) ss += __shfl_xor(ss, off, 64);
      // 0.216404256 = 1.2 * 0.125 * log2(e): scores come out in exp2 domain
      float scale = rsqrtf(ss * (1.0f / 64.0f) + 1.1920929e-07f) * (isq ? 0.216404256f : 1.2f);
      unsigned short o = f2bf(roped * scale);
      if (isq) Q[((size_t)(b * 16 + hs) * 2048 + s) * 64 + d] = o;
      else     K[((size_t)(b * 4 + (hs - 16)) * 2048 + s) * 64 + d] = o;
    } else {
      int kh = hs - 20;
      float vv = qkv[(size_t)token * 1536 + 1280 + kh * 64 + d];
      float dot = 0.f;
#pragma unroll
      for (int j = 0; j < 12; j++) dot += x[(size_t)token * 1024 + j] * wgate[kh * 12 + j];
      float gate = 3.0f / (1.0f + __expf(-dot));
      vv = fmaf(gate, ve[(size_t)token * 256 + kh * 64 + d], vv);
      Vt[((size_t)(b * 4 + kh) * 64 + d) * 2048 + s] = f2bf(vv);
    }
  }
}

// Causal flash attention, GQA 4:1, NO-MAX softmax (scores bounded: |s| <= 16.7 in exp2
// domain since q,k are rms-normed), deferred l reduction, reg-prefetch staging.
// Block = (pair, head, batch); pair handles q-tiles {pair, 31-pair} -> 33 k-iters/block.
__global__ __launch_bounds__(256) void flash_kernel(const unsigned short* __restrict__ Q,
                                                    const unsigned short* __restrict__ K,
                                                    const unsigned short* __restrict__ Vt,
                                                    unsigned short* __restrict__ Y) {
  __shared__ unsigned short Ks[64 * LROW];       // [key][dim]
  __shared__ unsigned short Vs[64 * LROW];       // [dim][key]  (from transposed global V)
  __shared__ unsigned short Ps[4 * 16 * LROW];   // per-wave P [q][key]
  int pair = blockIdx.x, h = blockIdx.y, b = blockIdx.z;
  int kh = h >> 2;
  int tid = threadIdx.x, wave = tid >> 6, lane = tid & 63, l15 = lane & 15, quad = lane >> 4;
  const unsigned short* Kg = K + (size_t)(b * 4 + kh) * 2048 * 64;
  const unsigned short* Vg = Vt + (size_t)(b * 4 + kh) * 64 * 2048;
  unsigned short* Pw = Ps + wave * 16 * LROW;
  int row0 = tid >> 3, col8 = (tid & 7) * 8;  // staging slot (2 rounds: row0, row0+32)

#pragma unroll
  for (int half = 0; half < 2; half++) {
    int qt = (half == 0) ? pair : 31 - pair;
    int q0 = qt * 64;
    const unsigned short* Qp = Q + (((size_t)(b * 16 + h) * 2048) + q0 + wave * 16 + l15) * 64;
    bf16x8 qf0 = *(const bf16x8*)(Qp + quad * 8);
    bf16x8 qf1 = *(const bf16x8*)(Qp + 32 + quad * 8);
    f32x4 acc[4];
#pragma unroll
    for (int i = 0; i < 4; i++) acc[i] = (f32x4){0.f, 0.f, 0.f, 0.f};
    float l_r[4] = {0.f, 0.f, 0.f, 0.f};

    // prefetch k-tile 0
    float4 pk0 = *(const float4*)(Kg + (size_t)row0 * 64 + col8);
    float4 pk1 = *(const float4*)(Kg + (size_t)(row0 + 32) * 64 + col8);
    float4 pv0 = *(const float4*)(Vg + (size_t)row0 * 2048 + col8);
    float4 pv1 = *(const float4*)(Vg + (size_t)(row0 + 32) * 2048 + col8);

    for (int kt = 0; kt <= qt; kt++) {
      int k0 = kt * 64;
      __syncthreads();  // prior consumers of Ks/Vs are done
      *(float4*)(Ks + row0 * LROW + col8) = pk0;
      *(float4*)(Ks + (row0 + 32) * LROW + col8) = pk1;
      *(float4*)(Vs + row0 * LROW + col8) = pv0;
      *(float4*)(Vs + (row0 + 32) * LROW + col8) = pv1;
      if (kt < qt) {  // prefetch next tile while computing this one
        int kn = k0 + 64;
        pk0 = *(const float4*)(Kg + (size_t)(kn + row0) * 64 + col8);
        pk1 = *(const float4*)(Kg + (size_t)(kn + row0 + 32) * 64 + col8);
        pv0 = *(const float4*)(Vg + (size_t)row0 * 2048 + kn + col8);
        pv1 = *(const float4*)(Vg + (size_t)(row0 + 32) * 2048 + kn + col8);
      }
      __syncthreads();

      f32x4 sv[4];
#pragma unroll
      for (int nt = 0; nt < 4; nt++) {
        sv[nt] = (f32x4){0.f, 0.f, 0.f, 0.f};
        bf16x8 b0 = *(const bf16x8*)(Ks + (nt * 16 + l15) * LROW + quad * 8);
        sv[nt] = __builtin_amdgcn_mfma_f32_16x16x32_bf16(qf0, b0, sv[nt], 0, 0, 0);
        bf16x8 b1 = *(const bf16x8*)(Ks + (nt * 16 + l15) * LROW + 32 + quad * 8);
        sv[nt] = __builtin_amdgcn_mfma_f32_16x16x32_bf16(qf1, b1, sv[nt], 0, 0, 0);
      }
      if (kt == qt) {  // diagonal tile: causal mask
        int qg = q0 + wave * 16 + quad * 4;
#pragma unroll
        for (int nt = 0; nt < 4; nt++) {
          int kg = k0 + nt * 16 + l15;
#pragma unroll
          for (int r = 0; r < 4; r++)
            if (kg > qg + r) sv[nt][r] = -1e30f;
        }
      }
      // p = exp2(s); accumulate per-lane l partials; stash P (bf16) for PV
#pragma unroll
      for (int nt = 0; nt < 4; nt++)
#pragma unroll
        for (int r = 0; r < 4; r++) {
          float p = exp2f(sv[nt][r]);
          l_r[r] += p;
          Pw[(quad * 4 + r) * LROW + nt * 16 + l15] = f2bf(p);
        }
      // per-wave LDS round-trip (C-layout -> A-layout); same-wave DS ordering, no barrier
#pragma unroll
      for (int step = 0; step < 2; step++) {
        bf16x8 pa = *(const bf16x8*)(Pw + l15 * LROW + step * 32 + quad * 8);
#pragma unroll
        for (int nt = 0; nt < 4; nt++) {
          bf16x8 vb = *(const bf16x8*)(Vs + (nt * 16 + l15) * LROW + step * 32 + quad * 8);
          acc[nt] = __builtin_amdgcn_mfma_f32_16x16x32_bf16(pa, vb, acc[nt], 0, 0, 0);
        }
      }
    }
    // deferred l reduction across the 16 key-lanes
#pragma unroll
    for (int r = 0; r < 4; r++)
#pragma unroll
      for (int off = 1; off < 16; off <<= 1) l_r[r] += __shfl_xor(l_r[r], off, 64);

    unsigned short* Yp = Y + ((size_t)b * 2048 + q0 + wave * 16) * 1024 + h * 64;
#pragma unroll
    for (int r = 0; r < 4; r++) {
      float inv = 1.f / l_r[r];
#pragma unroll
      for (int nt = 0; nt < 4; nt++)
        Yp[(size_t)(quad * 4 + r) * 1024 + nt * 16 + l15] = f2bf(acc[nt][r] * inv);
    }
  }
}

extern "C" void kernel_launch(void* const* d_in, const int* in_sizes, int n_in,
                              void* d_out, int out_size, void* d_ws, size_t ws_size,
                              hipStream_t stream) {
  const float* x     = (const float*)d_in[0];
  const float* ve    = (const float*)d_in[1];
  const float* cosb  = (const float*)d_in[2];
  const float* sinb  = (const float*)d_in[3];
  // d_in[4] attn_mask: causal, hard-coded
  const float* Wq    = (const float*)d_in[5];
  const float* Wk    = (const float*)d_in[6];
  const float* Wv    = (const float*)d_in[7];
  const float* Wproj = (const float*)d_in[8];
  const float* Wgate = (const float*)d_in[9];
  float* out = (float*)d_out;
  char* ws = (char*)d_ws;

  size_t o = 0;
  unsigned short* xb   = (unsigned short*)(ws + o); o += (size_t)4096 * 1024 * 2;   // x bf16
  unsigned short* wqkv = (unsigned short*)(ws + o); o += (size_t)1536 * 1024 * 2;   // [Wq;Wk;Wv] bf16
  unsigned short* wpj  = (unsigned short*)(ws + o); o += (size_t)1024 * 1024 * 2;   // Wproj bf16
  float*          qkvf = (float*)(ws + o);          o += (size_t)4096 * 1536 * 4;   // qkv fp32
  unsigned short* Qb   = (unsigned short*)(ws + o); o += (size_t)2 * 16 * 2048 * 64 * 2;
  unsigned short* Kb   = (unsigned short*)(ws + o); o += (size_t)2 * 4 * 2048 * 64 * 2;
  unsigned short* Vb   = (unsigned short*)(ws + o); o += (size_t)2 * 4 * 2048 * 64 * 2; // transposed
  unsigned short* Yb   = (unsigned short*)(ws + o); o += (size_t)4096 * 1024 * 2;   // attn out bf16

  hipLaunchKernelGGL(cvt_bf16_kernel, dim3(4096), dim3(256), 0, stream, x, xb, 1048576);
  hipLaunchKernelGGL(cvt_w_kernel, dim3(1536), dim3(256), 0, stream, Wq, Wk, Wv, wqkv);
  hipLaunchKernelGGL(cvt_bf16_kernel, dim3(1024), dim3(256), 0, stream, Wproj, wpj, 262144);

  hipLaunchKernelGGL(gemm_bt_kernel, dim3(24, 64), dim3(256), 0, stream, xb, wqkv, qkvf, 4096, 1536, 1024);
  hipLaunchKernelGGL(qkv_epilogue_kernel, dim3(4096), dim3(256), 0, stream,
                     qkvf, x, ve, cosb, sinb, Wgate, Qb, Kb, Vb);
  hipLaunchKernelGGL(flash_kernel, dim3(16, 16, 2), dim3(256), 0, stream, Qb, Kb, Vb, Yb);
  hipLaunchKernelGGL(gemm_bt_kernel, dim3(16, 64), dim3(256), 0, stream, Yb, wpj, out, 4096, 1024, 1024);
}

// Round 3
// 219.235 us; speedup vs baseline: 1.4729x; 1.0422x over previous
//
#include <hip/hip_runtime.h>
#include <hip/hip_bf16.h>
#include <math.h>

typedef short bf16x8 __attribute__((ext_vector_type(8)));
typedef float f32x4 __attribute__((ext_vector_type(4)));

#define LROW 72  // padded LDS row (bf16 elems): 144B stride -> 2-way bank alias (free)

__device__ __forceinline__ unsigned short f2bf(float f) {
  union { float f; unsigned int u; } v; v.f = f;
  unsigned int u = v.u;
  unsigned int r = (u + 0x7fffu + ((u >> 16) & 1u)) >> 16;
  return (unsigned short)r;
}

#if __has_builtin(__builtin_amdgcn_global_load_lds)
#define HAVE_GLD 1
__device__ __forceinline__ void gld16(const void* g, void* l) {
  __builtin_amdgcn_global_load_lds(
      (const __attribute__((address_space(1))) unsigned int*)g,
      (__attribute__((address_space(3))) unsigned int*)l, 16, 0, 0);
}
#else
#define HAVE_GLD 0
#endif

// fp32 -> bf16, 4 elems/thread
__global__ __launch_bounds__(256) void cvt_bf16_kernel(const float* __restrict__ src,
                                                       unsigned short* __restrict__ dst, int n4) {
  int i = blockIdx.x * 256 + threadIdx.x;
  if (i < n4) {
    float4 v = ((const float4*)src)[i];
    ushort4 o;
    o.x = f2bf(v.x); o.y = f2bf(v.y); o.z = f2bf(v.z); o.w = f2bf(v.w);
    ((ushort4*)dst)[i] = o;
  }
}

// Wq|Wk|Wv fp32 -> contiguous bf16 [1536][1024]; 1024 fp32 per block
__global__ __launch_bounds__(256) void cvt_w_kernel(const float* __restrict__ Wq,
                                                    const float* __restrict__ Wk,
                                                    const float* __restrict__ Wv,
                                                    unsigned short* __restrict__ dst) {
  int blk = blockIdx.x;
  const float* src;
  size_t off;
  if (blk < 1024)      { src = Wq; off = (size_t)blk * 1024; }
  else if (blk < 1280) { src = Wk; off = (size_t)(blk - 1024) * 1024; }
  else                 { src = Wv; off = (size_t)(blk - 1280) * 1024; }
  int i = threadIdx.x;
  float4 v = ((const float4*)(src + off))[i];
  ushort4 o;
  o.x = f2bf(v.x); o.y = f2bf(v.y); o.z = f2bf(v.z); o.w = f2bf(v.w);
  ((ushort4*)(dst + (size_t)blk * 1024))[i] = o;
}

// C[M][N] = A[M][K] x B[N][K]^T ; 128x128 tile, BK=64, m97-style global_load_lds staging.
// 4 waves in 2x2 grid, each computes 64x64 via 4x4 subtiles of 16x16x32 MFMA.
__global__ __launch_bounds__(256) void gemm128_kernel(const unsigned short* __restrict__ A,
                                                      const unsigned short* __restrict__ B,
                                                      float* __restrict__ C, int M, int N, int K) {
  __shared__ unsigned short As[128 * 64];
  __shared__ unsigned short Bs[128 * 64];
  int tid = threadIdx.x;
  int wave = tid >> 6, lane = tid & 63, l15 = lane & 15, quad = lane >> 4;
  int wm = (wave >> 1) * 64, wn = (wave & 1) * 64;
  int n0 = blockIdx.x * 128, m0 = blockIdx.y * 128;
  f32x4 acc[4][4];
#pragma unroll
  for (int i = 0; i < 4; i++)
#pragma unroll
    for (int j = 0; j < 4; j++) acc[i][j] = (f32x4){0.f, 0.f, 0.f, 0.f};
  int l8r = lane >> 3, l8c = (lane & 7) * 8;  // 8 lanes/row staging
  for (int k0 = 0; k0 < K; k0 += 64) {
    __syncthreads();
#if HAVE_GLD
#pragma unroll
    for (int i = 0; i < 4; i++) {
      int row = wave * 32 + i * 8;
      gld16(A + (size_t)(m0 + row + l8r) * K + k0 + l8c, As + row * 64 + lane * 8);
      gld16(B + (size_t)(n0 + row + l8r) * K + k0 + l8c, Bs + row * 64 + lane * 8);
    }
#else
#pragma unroll
    for (int i = 0; i < 4; i++) {
      int row = wave * 32 + i * 8;
      *(float4*)(As + row * 64 + lane * 8) = *(const float4*)(A + (size_t)(m0 + row + l8r) * K + k0 + l8c);
      *(float4*)(Bs + row * 64 + lane * 8) = *(const float4*)(B + (size_t)(n0 + row + l8r) * K + k0 + l8c);
    }
#endif
    __syncthreads();
#pragma unroll
    for (int kk = 0; kk < 64; kk += 32) {
      bf16x8 af[4], bf[4];
#pragma unroll
      for (int i = 0; i < 4; i++) af[i] = *(const bf16x8*)(As + (wm + i * 16 + l15) * 64 + kk + quad * 8);
#pragma unroll
      for (int j = 0; j < 4; j++) bf[j] = *(const bf16x8*)(Bs + (wn + j * 16 + l15) * 64 + kk + quad * 8);
#pragma unroll
      for (int i = 0; i < 4; i++)
#pragma unroll
        for (int j = 0; j < 4; j++)
          acc[i][j] = __builtin_amdgcn_mfma_f32_16x16x32_bf16(af[i], bf[j], acc[i][j], 0, 0, 0);
    }
  }
#pragma unroll
  for (int i = 0; i < 4; i++)
#pragma unroll
    for (int j = 0; j < 4; j++)
#pragma unroll
      for (int r = 0; r < 4; r++)
        C[(size_t)(m0 + wm + i * 16 + quad * 4 + r) * N + n0 + wn + j * 16 + l15] = acc[i][j][r];
}

// rope + rms-norm for q,k; gate+ve for v. One block per token, wave per head-slot.
// Q scaled by 1.2*0.125*log2(e) (softmax scale + exp2 fold), K by 1.2.
// V written TRANSPOSED [b][kh][d][s].
__global__ __launch_bounds__(256) void qkv_epilogue_kernel(
    const float* __restrict__ qkv, const float* __restrict__ x, const float* __restrict__ ve,
    const float* __restrict__ cosb, const float* __restrict__ sinb,
    const float* __restrict__ wgate, unsigned short* __restrict__ Q,
    unsigned short* __restrict__ K, unsigned short* __restrict__ Vt) {
  int token = blockIdx.x;
  int b = token >> 11, s = token & 2047;
  int wave = threadIdx.x >> 6, d = threadIdx.x & 63;
  float cv = cosb[s * 32 + (d & 31)];
  float sv = sinb[s * 32 + (d & 31)];
  for (int hs = wave; hs < 24; hs += 4) {
    if (hs < 20) {
      bool isq = hs < 16;
      int ch = isq ? hs * 64 + d : 1024 + (hs - 16) * 64 + d;
      float v0 = qkv[(size_t)token * 1536 + ch];
      float other = __shfl_xor(v0, 32, 64);
      float roped = (d < 32) ? fmaf(v0, cv, other * sv) : fmaf(v0, cv, -other * sv);
      float ss = roped * roped;
#pragma unroll
      for (int off = 1; off < 64; off <<= 1) ss += __shfl_xor(ss, off, 64);
      // 0.216404256 = 1.2 * 0.125 * log2(e): scores come out in exp2 domain
      float scale = rsqrtf(ss * (1.0f / 64.0f) + 1.1920929e-07f) * (isq ? 0.216404256f : 1.2f);
      unsigned short o = f2bf(roped * scale);
      if (isq) Q[((size_t)(b * 16 + hs) * 2048 + s) * 64 + d] = o;
      else     K[((size_t)(b * 4 + (hs - 16)) * 2048 + s) * 64 + d] = o;
    } else {
      int kh = hs - 20;
      float vv = qkv[(size_t)token * 1536 + 1280 + kh * 64 + d];
      float dot = 0.f;
#pragma unroll
      for (int j = 0; j < 12; j++) dot += x[(size_t)token * 1024 + j] * wgate[kh * 12 + j];
      float gate = 3.0f / (1.0f + __expf(-dot));
      vv = fmaf(gate, ve[(size_t)token * 256 + kh * 64 + d], vv);
      Vt[((size_t)(b * 4 + kh) * 64 + d) * 2048 + s] = f2bf(vv);
    }
  }
}

// Causal flash attention, GQA 4:1, NO-MAX softmax (q,k rms-normed -> |s|<=16.7 exp2-domain),
// S^T = K*Q^T so each lane holds 4 CONSECUTIVE KEYS at fixed q: P transpose-write becomes
// pack2+ds_write_b64. Deferred single-accumulator l. Reg-prefetch K/V staging.
// Block = (pair, head, batch); handles q-tiles {pair, 31-pair} -> 33 k-iters/block.
__global__ __launch_bounds__(256) void flash_kernel(const unsigned short* __restrict__ Q,
                                                    const unsigned short* __restrict__ K,
                                                    const unsigned short* __restrict__ Vt,
                                                    unsigned short* __restrict__ Y) {
  __shared__ unsigned short Ks[64 * LROW];       // [key][dim]
  __shared__ unsigned short Vs[64 * LROW];       // [dim][key]  (from transposed global V)
  __shared__ unsigned short Ps[4 * 16 * LROW];   // per-wave P [q][key]
  int pair = blockIdx.x, h = blockIdx.y, b = blockIdx.z;
  int kh = h >> 2;
  int tid = threadIdx.x, wave = tid >> 6, lane = tid & 63, l15 = lane & 15, quad = lane >> 4;
  const unsigned short* Kg = K + (size_t)(b * 4 + kh) * 2048 * 64;
  const unsigned short* Vg = Vt + (size_t)(b * 4 + kh) * 64 * 2048;
  unsigned short* Pw = Ps + wave * 16 * LROW;
  int row0 = tid >> 3, col8 = (tid & 7) * 8;  // staging slot (2 rounds: row0, row0+32)

#pragma unroll
  for (int half = 0; half < 2; half++) {
    int qt = (half == 0) ? pair : 31 - pair;
    int q0 = qt * 64;
    const unsigned short* Qp = Q + (((size_t)(b * 16 + h) * 2048) + q0 + wave * 16 + l15) * 64;
    bf16x8 qf0 = *(const bf16x8*)(Qp + quad * 8);
    bf16x8 qf1 = *(const bf16x8*)(Qp + 32 + quad * 8);
    f32x4 acc[4];
#pragma unroll
    for (int i = 0; i < 4; i++) acc[i] = (f32x4){0.f, 0.f, 0.f, 0.f};
    float l_lane = 0.f;

    // prefetch k-tile 0
    float4 pk0 = *(const float4*)(Kg + (size_t)row0 * 64 + col8);
    float4 pk1 = *(const float4*)(Kg + (size_t)(row0 + 32) * 64 + col8);
    float4 pv0 = *(const float4*)(Vg + (size_t)row0 * 2048 + col8);
    float4 pv1 = *(const float4*)(Vg + (size_t)(row0 + 32) * 2048 + col8);

    for (int kt = 0; kt <= qt; kt++) {
      int k0 = kt * 64;
      __syncthreads();  // prior consumers of Ks/Vs are done
      *(float4*)(Ks + row0 * LROW + col8) = pk0;
      *(float4*)(Ks + (row0 + 32) * LROW + col8) = pk1;
      *(float4*)(Vs + row0 * LROW + col8) = pv0;
      *(float4*)(Vs + (row0 + 32) * LROW + col8) = pv1;
      if (kt < qt) {  // prefetch next tile while computing this one
        int kn = k0 + 64;
        pk0 = *(const float4*)(Kg + (size_t)(kn + row0) * 64 + col8);
        pk1 = *(const float4*)(Kg + (size_t)(kn + row0 + 32) * 64 + col8);
        pv0 = *(const float4*)(Vg + (size_t)row0 * 2048 + kn + col8);
        pv1 = *(const float4*)(Vg + (size_t)(row0 + 32) * 2048 + kn + col8);
      }
      __syncthreads();

      // S^T tiles: A = K rows (m=key), B = Q (n=q). sv[mt][r] = S[q=l15][key=mt*16+quad*4+r]
      f32x4 sv[4];
#pragma unroll
      for (int mt = 0; mt < 4; mt++) {
        sv[mt] = (f32x4){0.f, 0.f, 0.f, 0.f};
        bf16x8 k0f = *(const bf16x8*)(Ks + (mt * 16 + l15) * LROW + quad * 8);
        sv[mt] = __builtin_amdgcn_mfma_f32_16x16x32_bf16(k0f, qf0, sv[mt], 0, 0, 0);
        bf16x8 k1f = *(const bf16x8*)(Ks + (mt * 16 + l15) * LROW + 32 + quad * 8);
        sv[mt] = __builtin_amdgcn_mfma_f32_16x16x32_bf16(k1f, qf1, sv[mt], 0, 0, 0);
      }
      if (kt == qt) {  // diagonal tile: causal mask (key > q)
        int qg = q0 + wave * 16 + l15;
#pragma unroll
        for (int mt = 0; mt < 4; mt++) {
          int kg = k0 + mt * 16 + quad * 4;
#pragma unroll
          for (int r = 0; r < 4; r++)
            if (kg + r > qg) sv[mt][r] = -1e30f;
        }
      }
      // p = exp2(s); single-accumulator l; truncate-pack 4 consecutive keys -> ds_write_b64
#pragma unroll
      for (int mt = 0; mt < 4; mt++) {
        float p0 = exp2f(sv[mt][0]), p1 = exp2f(sv[mt][1]);
        float p2 = exp2f(sv[mt][2]), p3 = exp2f(sv[mt][3]);
        l_lane += (p0 + p1) + (p2 + p3);
        unsigned int lo = (__float_as_uint(p1) & 0xffff0000u) | (__float_as_uint(p0) >> 16);
        unsigned int hi = (__float_as_uint(p3) & 0xffff0000u) | (__float_as_uint(p2) >> 16);
        *(uint2*)(Pw + l15 * LROW + mt * 16 + quad * 4) = make_uint2(lo, hi);
      }
      // PV: A = P rows (m=q=l15), B = V^T rows (n=d). Same-wave DS ordering, no barrier.
#pragma unroll
      for (int step = 0; step < 2; step++) {
        bf16x8 pa = *(const bf16x8*)(Pw + l15 * LROW + step * 32 + quad * 8);
#pragma unroll
        for (int nt = 0; nt < 4; nt++) {
          bf16x8 vb = *(const bf16x8*)(Vs + (nt * 16 + l15) * LROW + step * 32 + quad * 8);
          acc[nt] = __builtin_amdgcn_mfma_f32_16x16x32_bf16(pa, vb, acc[nt], 0, 0, 0);
        }
      }
    }
    // l: reduce over the 4 lane-groups (same l15), then fetch per-row value
    l_lane += __shfl_xor(l_lane, 16, 64);
    l_lane += __shfl_xor(l_lane, 32, 64);

    unsigned short* Yp = Y + ((size_t)b * 2048 + q0 + wave * 16) * 1024 + h * 64;
#pragma unroll
    for (int r = 0; r < 4; r++) {
      float inv = 1.f / __shfl(l_lane, quad * 4 + r, 64);
#pragma unroll
      for (int nt = 0; nt < 4; nt++)
        Yp[(size_t)(quad * 4 + r) * 1024 + nt * 16 + l15] = f2bf(acc[nt][r] * inv);
    }
  }
}

extern "C" void kernel_launch(void* const* d_in, const int* in_sizes, int n_in,
                              void* d_out, int out_size, void* d_ws, size_t ws_size,
                              hipStream_t stream) {
  const float* x     = (const float*)d_in[0];
  const float* ve    = (const float*)d_in[1];
  const float* cosb  = (const float*)d_in[2];
  const float* sinb  = (const float*)d_in[3];
  // d_in[4] attn_mask: causal, hard-coded
  const float* Wq    = (const float*)d_in[5];
  const float* Wk    = (const float*)d_in[6];
  const float* Wv    = (const float*)d_in[7];
  const float* Wproj = (const float*)d_in[8];
  const float* Wgate = (const float*)d_in[9];
  float* out = (float*)d_out;
  char* ws = (char*)d_ws;

  size_t o = 0;
  unsigned short* xb   = (unsigned short*)(ws + o); o += (size_t)4096 * 1024 * 2;   // x bf16
  unsigned short* wqkv = (unsigned short*)(ws + o); o += (size_t)1536 * 1024 * 2;   // [Wq;Wk;Wv] bf16
  unsigned short* wpj  = (unsigned short*)(ws + o); o += (size_t)1024 * 1024 * 2;   // Wproj bf16
  float*          qkvf = (float*)(ws + o);          o += (size_t)4096 * 1536 * 4;   // qkv fp32
  unsigned short* Qb   = (unsigned short*)(ws + o); o += (size_t)2 * 16 * 2048 * 64 * 2;
  unsigned short* Kb   = (unsigned short*)(ws + o); o += (size_t)2 * 4 * 2048 * 64 * 2;
  unsigned short* Vb   = (unsigned short*)(ws + o); o += (size_t)2 * 4 * 2048 * 64 * 2; // transposed
  unsigned short* Yb   = (unsigned short*)(ws + o); o += (size_t)4096 * 1024 * 2;   // attn out bf16

  hipLaunchKernelGGL(cvt_bf16_kernel, dim3(4096), dim3(256), 0, stream, x, xb, 1048576);
  hipLaunchKernelGGL(cvt_w_kernel, dim3(1536), dim3(256), 0, stream, Wq, Wk, Wv, wqkv);
  hipLaunchKernelGGL(cvt_bf16_kernel, dim3(1024), dim3(256), 0, stream, Wproj, wpj, 262144);

  hipLaunchKernelGGL(gemm128_kernel, dim3(12, 32), dim3(256), 0, stream, xb, wqkv, qkvf, 4096, 1536, 1024);
  hipLaunchKernelGGL(qkv_epilogue_kernel, dim3(4096), dim3(256), 0, stream,
                     qkvf, x, ve, cosb, sinb, Wgate, Qb, Kb, Vb);
  hipLaunchKernelGGL(flash_kernel, dim3(16, 16, 2), dim3(256), 0, stream, Qb, Kb, Vb, Yb);
  hipLaunchKernelGGL(gemm128_kernel, dim3(8, 32), dim3(256), 0, stream, Yb, wpj, out, 4096, 1024, 1024);
}

// Round 4
// 210.135 us; speedup vs baseline: 1.5367x; 1.0433x over previous
//
#include <hip/hip_runtime.h>
#include <hip/hip_bf16.h>
#include <math.h>

typedef short bf16x8 __attribute__((ext_vector_type(8)));
typedef float f32x4 __attribute__((ext_vector_type(4)));

#define LROW 72  // padded LDS row (bf16 elems) for flash: 144B stride, 2-way alias (free)

__device__ __forceinline__ unsigned short f2bf(float f) {
  union { float f; unsigned int u; } v; v.f = f;
  unsigned int u = v.u;
  unsigned int r = (u + 0x7fffu + ((u >> 16) & 1u)) >> 16;
  return (unsigned short)r;
}

#if __has_builtin(__builtin_amdgcn_global_load_lds)
#define HAVE_GLD 1
__device__ __forceinline__ void gld16(const void* g, void* l) {
  __builtin_amdgcn_global_load_lds(
      (const __attribute__((address_space(1))) unsigned int*)g,
      (__attribute__((address_space(3))) unsigned int*)l, 16, 0, 0);
}
#else
#define HAVE_GLD 0
#endif

// fp32 -> bf16, 4 elems/thread
__global__ __launch_bounds__(256) void cvt_bf16_kernel(const float* __restrict__ src,
                                                       unsigned short* __restrict__ dst, int n4) {
  int i = blockIdx.x * 256 + threadIdx.x;
  if (i < n4) {
    float4 v = ((const float4*)src)[i];
    ushort4 o;
    o.x = f2bf(v.x); o.y = f2bf(v.y); o.z = f2bf(v.z); o.w = f2bf(v.w);
    ((ushort4*)dst)[i] = o;
  }
}

// Wq|Wk|Wv fp32 -> contiguous bf16 [1536][1024]; 1024 fp32 per block
__global__ __launch_bounds__(256) void cvt_w_kernel(const float* __restrict__ Wq,
                                                    const float* __restrict__ Wk,
                                                    const float* __restrict__ Wv,
                                                    unsigned short* __restrict__ dst) {
  int blk = blockIdx.x;
  const float* src;
  size_t off;
  if (blk < 1024)      { src = Wq; off = (size_t)blk * 1024; }
  else if (blk < 1280) { src = Wk; off = (size_t)(blk - 1024) * 1024; }
  else                 { src = Wv; off = (size_t)(blk - 1280) * 1024; }
  int i = threadIdx.x;
  float4 v = ((const float4*)(src + off))[i];
  ushort4 o;
  o.x = f2bf(v.x); o.y = f2bf(v.y); o.z = f2bf(v.z); o.w = f2bf(v.w);
  ((ushort4*)(dst + (size_t)blk * 1024))[i] = o;
}

// C[M][N] = A[M][K] x B[N][K]^T ; 128x128 tile, BK=64, global_load_lds(16B) staging,
// XOR-swizzled LDS (chunk c of row r stored at c^(r&7)) -> conflict-free b128 reads
// AND contiguous wave-ordered gld dest. M,N multiples of 128, K of 64.
__global__ __launch_bounds__(256) void gemm128_kernel(const unsigned short* __restrict__ A,
                                                      const unsigned short* __restrict__ B,
                                                      float* __restrict__ C, int M, int N, int K) {
  __shared__ unsigned short As[128 * 64];
  __shared__ unsigned short Bs[128 * 64];
  int tid = threadIdx.x;
  int wave = tid >> 6, lane = tid & 63, l15 = lane & 15, quad = lane >> 4;
  int wm = (wave >> 1) * 64, wn = (wave & 1) * 64;
  int n0 = blockIdx.x * 128, m0 = blockIdx.y * 128;
  f32x4 acc[4][4];
#pragma unroll
  for (int i = 0; i < 4; i++)
#pragma unroll
    for (int j = 0; j < 4; j++) acc[i][j] = (f32x4){0.f, 0.f, 0.f, 0.f};
  int srow = lane >> 3;                      // staging row within 8-row group
  int scol = ((lane & 7) ^ srow) * 8;        // swizzled source chunk (coalesced permute)
  for (int k0 = 0; k0 < K; k0 += 64) {
    __syncthreads();
#if HAVE_GLD
#pragma unroll
    for (int i = 0; i < 4; i++) {
      int row = wave * 32 + i * 8;
      gld16(A + (size_t)(m0 + row + srow) * K + k0 + scol, As + row * 64 + lane * 8);
      gld16(B + (size_t)(n0 + row + srow) * K + k0 + scol, Bs + row * 64 + lane * 8);
    }
#else
#pragma unroll
    for (int i = 0; i < 4; i++) {
      int row = wave * 32 + i * 8;
      *(float4*)(As + row * 64 + lane * 8) = *(const float4*)(A + (size_t)(m0 + row + srow) * K + k0 + scol);
      *(float4*)(Bs + row * 64 + lane * 8) = *(const float4*)(B + (size_t)(n0 + row + srow) * K + k0 + scol);
    }
#endif
    __syncthreads();
#pragma unroll
    for (int s = 0; s < 2; s++) {  // kk = s*32
      bf16x8 af[4], bf[4];
#pragma unroll
      for (int i = 0; i < 4; i++)
        af[i] = *(const bf16x8*)(As + (wm + i * 16 + l15) * 64 + (((s * 4 + quad) ^ (l15 & 7)) * 8));
#pragma unroll
      for (int j = 0; j < 4; j++)
        bf[j] = *(const bf16x8*)(Bs + (wn + j * 16 + l15) * 64 + (((s * 4 + quad) ^ (l15 & 7)) * 8));
#pragma unroll
      for (int i = 0; i < 4; i++)
#pragma unroll
        for (int j = 0; j < 4; j++)
          acc[i][j] = __builtin_amdgcn_mfma_f32_16x16x32_bf16(af[i], bf[j], acc[i][j], 0, 0, 0);
    }
  }
#pragma unroll
  for (int i = 0; i < 4; i++)
#pragma unroll
    for (int j = 0; j < 4; j++)
#pragma unroll
      for (int r = 0; r < 4; r++)
        C[(size_t)(m0 + wm + i * 16 + quad * 4 + r) * N + n0 + wn + j * 16 + l15] = acc[i][j][r];
}

// rope + rms-norm for q,k; gate+ve for v. One block per token, wave per head-slot.
// Q scaled by 1.2*0.125*log2(e) (softmax scale + exp2 fold), K by 1.2.
// V written TRANSPOSED [b][kh][d][s].
__global__ __launch_bounds__(256) void qkv_epilogue_kernel(
    const float* __restrict__ qkv, const float* __restrict__ x, const float* __restrict__ ve,
    const float* __restrict__ cosb, const float* __restrict__ sinb,
    const float* __restrict__ wgate, unsigned short* __restrict__ Q,
    unsigned short* __restrict__ K, unsigned short* __restrict__ Vt) {
  int token = blockIdx.x;
  int b = token >> 11, s = token & 2047;
  int wave = threadIdx.x >> 6, d = threadIdx.x & 63;
  float cv = cosb[s * 32 + (d & 31)];
  float sv = sinb[s * 32 + (d & 31)];
  for (int hs = wave; hs < 24; hs += 4) {
    if (hs < 20) {
      bool isq = hs < 16;
      int ch = isq ? hs * 64 + d : 1024 + (hs - 16) * 64 + d;
      float v0 = qkv[(size_t)token * 1536 + ch];
      float other = __shfl_xor(v0, 32, 64);
      float roped = (d < 32) ? fmaf(v0, cv, other * sv) : fmaf(v0, cv, -other * sv);
      float ss = roped * roped;
#pragma unroll
      for (int off = 1; off < 64; off <<= 1) ss += __shfl_xor(ss, off, 64);
      // 0.216404256 = 1.2 * 0.125 * log2(e): scores come out in exp2 domain
      float scale = rsqrtf(ss * (1.0f / 64.0f) + 1.1920929e-07f) * (isq ? 0.216404256f : 1.2f);
      unsigned short o = f2bf(roped * scale);
      if (isq) Q[((size_t)(b * 16 + hs) * 2048 + s) * 64 + d] = o;
      else     K[((size_t)(b * 4 + (hs - 16)) * 2048 + s) * 64 + d] = o;
    } else {
      int kh = hs - 20;
      float vv = qkv[(size_t)token * 1536 + 1280 + kh * 64 + d];
      float dot = 0.f;
#pragma unroll
      for (int j = 0; j < 12; j++) dot += x[(size_t)token * 1024 + j] * wgate[kh * 12 + j];
      float gate = 3.0f / (1.0f + __expf(-dot));
      vv = fmaf(gate, ve[(size_t)token * 256 + kh * 64 + d], vv);
      Vt[((size_t)(b * 4 + kh) * 64 + d) * 2048 + s] = f2bf(vv);
    }
  }
}

// Causal flash attention, GQA 4:1, NO-MAX softmax, SPLIT-K x2 (partials in same exp2
// domain: merge = plain add). Block = (pair, h, b*2+c); q-tiles {pair, 31-pair}, key
// chunk c -> exactly 16 or 17 k-iters per block. Partials: acc bf16, l fp32.
__global__ __launch_bounds__(256) void flash_kernel(const unsigned short* __restrict__ Q,
                                                    const unsigned short* __restrict__ K,
                                                    const unsigned short* __restrict__ Vt,
                                                    unsigned short* __restrict__ accP,
                                                    float* __restrict__ lP) {
  __shared__ unsigned short Ks[64 * LROW];       // [key][dim]
  __shared__ unsigned short Vs[64 * LROW];       // [dim][key]
  __shared__ unsigned short Ps[4 * 16 * LROW];   // per-wave P [q][key]
  int pair = blockIdx.x, h = blockIdx.y, bc = blockIdx.z;
  int b = bc >> 1, c = bc & 1;
  int hb = b * 16 + h;
  int kh = h >> 2;
  int tid = threadIdx.x, wave = tid >> 6, lane = tid & 63, l15 = lane & 15, quad = lane >> 4;
  const unsigned short* Kg = K + (size_t)(b * 4 + kh) * 2048 * 64;
  const unsigned short* Vg = Vt + (size_t)(b * 4 + kh) * 64 * 2048;
  unsigned short* Pw = Ps + wave * 16 * LROW;
  int row0 = tid >> 3, col8 = (tid & 7) * 8;  // staging slot (2 rounds: row0, row0+32)

#pragma unroll
  for (int half = 0; half < 2; half++) {
    int qt = (half == 0) ? pair : 31 - pair;
    int c0t = (c == 0) ? 0 : (qt + 2) >> 1;       // chunk key-tile range [c0t, c1t)
    int c1t = (c == 0) ? ((qt + 2) >> 1) : qt + 1;
    int q0 = qt * 64;
    const unsigned short* Qp = Q + (((size_t)hb * 2048) + q0 + wave * 16 + l15) * 64;
    bf16x8 qf0 = *(const bf16x8*)(Qp + quad * 8);
    bf16x8 qf1 = *(const bf16x8*)(Qp + 32 + quad * 8);
    f32x4 acc[4];
#pragma unroll
    for (int i = 0; i < 4; i++) acc[i] = (f32x4){0.f, 0.f, 0.f, 0.f};
    float l_lane = 0.f;

    if (c1t > c0t) {
      // prefetch first k-tile of chunk
      int kf = c0t * 64;
      float4 pk0 = *(const float4*)(Kg + (size_t)(kf + row0) * 64 + col8);
      float4 pk1 = *(const float4*)(Kg + (size_t)(kf + row0 + 32) * 64 + col8);
      float4 pv0 = *(const float4*)(Vg + (size_t)row0 * 2048 + kf + col8);
      float4 pv1 = *(const float4*)(Vg + (size_t)(row0 + 32) * 2048 + kf + col8);

      for (int kt = c0t; kt < c1t; kt++) {
        int k0 = kt * 64;
        __syncthreads();  // prior consumers of Ks/Vs done
        *(float4*)(Ks + row0 * LROW + col8) = pk0;
        *(float4*)(Ks + (row0 + 32) * LROW + col8) = pk1;
        *(float4*)(Vs + row0 * LROW + col8) = pv0;
        *(float4*)(Vs + (row0 + 32) * LROW + col8) = pv1;
        if (kt + 1 < c1t) {
          int kn = k0 + 64;
          pk0 = *(const float4*)(Kg + (size_t)(kn + row0) * 64 + col8);
          pk1 = *(const float4*)(Kg + (size_t)(kn + row0 + 32) * 64 + col8);
          pv0 = *(const float4*)(Vg + (size_t)row0 * 2048 + kn + col8);
          pv1 = *(const float4*)(Vg + (size_t)(row0 + 32) * 2048 + kn + col8);
        }
        __syncthreads();

        // S^T: A = K rows (m=key), B = Q (n=q). sv[mt][r] = S[q=l15][key=mt*16+quad*4+r]
        f32x4 sv[4];
#pragma unroll
        for (int mt = 0; mt < 4; mt++) {
          sv[mt] = (f32x4){0.f, 0.f, 0.f, 0.f};
          bf16x8 k0f = *(const bf16x8*)(Ks + (mt * 16 + l15) * LROW + quad * 8);
          sv[mt] = __builtin_amdgcn_mfma_f32_16x16x32_bf16(k0f, qf0, sv[mt], 0, 0, 0);
          bf16x8 k1f = *(const bf16x8*)(Ks + (mt * 16 + l15) * LROW + 32 + quad * 8);
          sv[mt] = __builtin_amdgcn_mfma_f32_16x16x32_bf16(k1f, qf1, sv[mt], 0, 0, 0);
        }
        if (kt == qt) {  // diagonal tile: causal mask (key > q)
          int qg = q0 + wave * 16 + l15;
#pragma unroll
          for (int mt = 0; mt < 4; mt++) {
            int kg = k0 + mt * 16 + quad * 4;
#pragma unroll
            for (int r = 0; r < 4; r++)
              if (kg + r > qg) sv[mt][r] = -1e30f;
          }
        }
        // p = exp2(s); per-lane l; v_perm truncate-pack 4 consecutive keys -> ds_write_b64
#pragma unroll
        for (int mt = 0; mt < 4; mt++) {
          float p0 = __builtin_amdgcn_exp2f(sv[mt][0]);
          float p1 = __builtin_amdgcn_exp2f(sv[mt][1]);
          float p2 = __builtin_amdgcn_exp2f(sv[mt][2]);
          float p3 = __builtin_amdgcn_exp2f(sv[mt][3]);
          l_lane += (p0 + p1) + (p2 + p3);
          unsigned int lo = __builtin_amdgcn_perm(__float_as_uint(p1), __float_as_uint(p0), 0x07060302u);
          unsigned int hi = __builtin_amdgcn_perm(__float_as_uint(p3), __float_as_uint(p2), 0x07060302u);
          *(uint2*)(Pw + l15 * LROW + mt * 16 + quad * 4) = make_uint2(lo, hi);
        }
        // PV: A = P rows (m=q=l15), B = V^T rows (n=d). Same-wave DS ordering, no barrier.
#pragma unroll
        for (int step = 0; step < 2; step++) {
          bf16x8 pa = *(const bf16x8*)(Pw + l15 * LROW + step * 32 + quad * 8);
#pragma unroll
          for (int nt = 0; nt < 4; nt++) {
            bf16x8 vb = *(const bf16x8*)(Vs + (nt * 16 + l15) * LROW + step * 32 + quad * 8);
            acc[nt] = __builtin_amdgcn_mfma_f32_16x16x32_bf16(pa, vb, acc[nt], 0, 0, 0);
          }
        }
      }
    }
    // reduce l over the 4 lane-groups (same q=l15)
    l_lane += __shfl_xor(l_lane, 16, 64);
    l_lane += __shfl_xor(l_lane, 32, 64);

    size_t slot = (size_t)(c * 32 + hb) * 2048 + q0 + wave * 16;
    if (lane < 16) lP[slot + l15] = l_lane;
    unsigned short* aP = accP + slot * 64;
#pragma unroll
    for (int r = 0; r < 4; r++)
#pragma unroll
      for (int nt = 0; nt < 4; nt++)
        aP[(size_t)(quad * 4 + r) * 64 + nt * 16 + l15] = f2bf(acc[nt][r]);
  }
}

// merge split-K partials: Y = (a0+a1)/(l0+l1), bf16 out. 4 d-elems/thread.
__global__ __launch_bounds__(256) void merge_kernel(const unsigned short* __restrict__ accP,
                                                    const float* __restrict__ lP,
                                                    unsigned short* __restrict__ Y) {
  int t = blockIdx.x * 256 + threadIdx.x;      // 1,048,576 total
  int d4 = (t & 15) * 4;
  int q  = (t >> 4) & 2047;
  int hb = t >> 15;                            // b*16 + h
  const size_t CSTR = (size_t)32 * 2048 * 64;
  size_t pi = ((size_t)hb * 2048 + q) * 64 + d4;
  ushort4 a0 = *(const ushort4*)(accP + pi);
  ushort4 a1 = *(const ushort4*)(accP + pi + CSTR);
  float l = lP[hb * 2048 + q] + lP[32 * 2048 + hb * 2048 + q];
  float inv = 1.f / l;
  float y0 = (__uint_as_float((unsigned)a0.x << 16) + __uint_as_float((unsigned)a1.x << 16)) * inv;
  float y1 = (__uint_as_float((unsigned)a0.y << 16) + __uint_as_float((unsigned)a1.y << 16)) * inv;
  float y2 = (__uint_as_float((unsigned)a0.z << 16) + __uint_as_float((unsigned)a1.z << 16)) * inv;
  float y3 = (__uint_as_float((unsigned)a0.w << 16) + __uint_as_float((unsigned)a1.w << 16)) * inv;
  ushort4 o;
  o.x = f2bf(y0); o.y = f2bf(y1); o.z = f2bf(y2); o.w = f2bf(y3);
  int b = hb >> 4, hh = hb & 15;
  *(ushort4*)(Y + ((size_t)(b * 2048 + q) * 1024) + hh * 64 + d4) = o;
}

extern "C" void kernel_launch(void* const* d_in, const int* in_sizes, int n_in,
                              void* d_out, int out_size, void* d_ws, size_t ws_size,
                              hipStream_t stream) {
  const float* x     = (const float*)d_in[0];
  const float* ve    = (const float*)d_in[1];
  const float* cosb  = (const float*)d_in[2];
  const float* sinb  = (const float*)d_in[3];
  // d_in[4] attn_mask: causal, hard-coded
  const float* Wq    = (const float*)d_in[5];
  const float* Wk    = (const float*)d_in[6];
  const float* Wv    = (const float*)d_in[7];
  const float* Wproj = (const float*)d_in[8];
  const float* Wgate = (const float*)d_in[9];
  float* out = (float*)d_out;
  char* ws = (char*)d_ws;

  size_t o = 0;
  unsigned short* xb   = (unsigned short*)(ws + o); o += (size_t)4096 * 1024 * 2;   // x bf16
  unsigned short* wqkv = (unsigned short*)(ws + o); o += (size_t)1536 * 1024 * 2;   // [Wq;Wk;Wv] bf16
  unsigned short* wpj  = (unsigned short*)(ws + o); o += (size_t)1024 * 1024 * 2;   // Wproj bf16
  char*           qkvr = ws + o;                    o += (size_t)4096 * 1536 * 4;   // qkv fp32 / flash partials
  unsigned short* Qb   = (unsigned short*)(ws + o); o += (size_t)2 * 16 * 2048 * 64 * 2;
  unsigned short* Kb   = (unsigned short*)(ws + o); o += (size_t)2 * 4 * 2048 * 64 * 2;
  unsigned short* Vb   = (unsigned short*)(ws + o); o += (size_t)2 * 4 * 2048 * 64 * 2; // transposed
  unsigned short* Yb   = (unsigned short*)(ws + o); o += (size_t)4096 * 1024 * 2;   // attn out bf16

  float* qkvf = (float*)qkvr;
  // flash partials overlay the (dead-after-epilogue) qkvf region: 16.8MB acc + 0.5MB l <= 25.2MB
  unsigned short* accP = (unsigned short*)qkvr;
  float* lP = (float*)(qkvr + (size_t)2 * 2 * 16 * 2048 * 64 * 2);

  hipLaunchKernelGGL(cvt_bf16_kernel, dim3(4096), dim3(256), 0, stream, x, xb, 1048576);
  hipLaunchKernelGGL(cvt_w_kernel, dim3(1536), dim3(256), 0, stream, Wq, Wk, Wv, wqkv);
  hipLaunchKernelGGL(cvt_bf16_kernel, dim3(1024), dim3(256), 0, stream, Wproj, wpj, 262144);

  hipLaunchKernelGGL(gemm128_kernel, dim3(12, 32), dim3(256), 0, stream, xb, wqkv, qkvf, 4096, 1536, 1024);
  hipLaunchKernelGGL(qkv_epilogue_kernel, dim3(4096), dim3(256), 0, stream,
                     qkvf, x, ve, cosb, sinb, Wgate, Qb, Kb, Vb);
  hipLaunchKernelGGL(flash_kernel, dim3(16, 16, 4), dim3(256), 0, stream, Qb, Kb, Vb, accP, lP);
  hipLaunchKernelGGL(merge_kernel, dim3(4096), dim3(256), 0, stream, accP, lP, Yb);
  hipLaunchKernelGGL(gemm128_kernel, dim3(8, 32), dim3(256), 0, stream, Yb, wpj, out, 4096, 1024, 1024);
}